// Round 8
// baseline (505.813 us; speedup 1.0000x reference)
//
#include <hip/hip_runtime.h>

typedef __attribute__((ext_vector_type(8))) short bf16x8;
typedef __attribute__((ext_vector_type(4))) float f32x4;
typedef unsigned short u16;

__device__ __forceinline__ u16 f2bf(float f) {
  union { float f; unsigned u; } v; v.f = f;
  unsigned r = v.u + 0x7fffu + ((v.u >> 16) & 1u);   // RNE
  return (u16)(r >> 16);
}
__device__ __forceinline__ float bf2f(u16 u) {
  union { unsigned u; float f; } v; v.u = ((unsigned)u) << 16;
  return v.f;
}
__device__ __forceinline__ void gload16(const void* g, void* l) {
  __builtin_amdgcn_global_load_lds((const __attribute__((address_space(1))) void*)g,
                                   (__attribute__((address_space(3))) void*)l, 16, 0, 0);
}

#define PH_BAR __builtin_amdgcn_s_barrier()
#define LGKM0  asm volatile("s_waitcnt lgkmcnt(0)" ::: "memory")
#define VM6    asm volatile("s_waitcnt vmcnt(6)" ::: "memory")
#define VM0    asm volatile("s_waitcnt vmcnt(0)" ::: "memory")

// ---------------- fp32 -> bf16 converter (4 elems/thread) ----------------
__global__ void sab_cvt_kernel(const float* __restrict__ src, u16* __restrict__ dst, int n4) {
  int i = blockIdx.x * blockDim.x + threadIdx.x;
  if (i >= n4) return;
  float4 f = reinterpret_cast<const float4*>(src)[i];
  ushort4 o; o.x = f2bf(f.x); o.y = f2bf(f.y); o.z = f2bf(f.z); o.w = f2bf(f.w);
  reinterpret_cast<ushort4*>(dst)[i] = o;
}

// ------------- window partition + convert: xw[r][c] = x[xrow(r)][c] -------------
__global__ void sab_xw_kernel(const float* __restrict__ x, u16* __restrict__ xw) {
  const int r = blockIdx.x;                 // 0..32767 (window-token row)
  const int w = r >> 8, tt = r & 255;
  const int b = w >> 4, h1 = (w >> 2) & 3, w1 = w & 3;
  const int i = tt >> 4, j = tt & 15;
  const long xrow = (long)b * 4096 + (h1 * 16 + i) * 64 + w1 * 16 + j;
  const float4* src = reinterpret_cast<const float4*>(x + xrow * 768);
  ushort4* dst = reinterpret_cast<ushort4*>(xw + (long)r * 768);
  const int c = threadIdx.x;                // 0..191, 192*4 = 768
  float4 f = src[c];
  ushort4 o; o.x = f2bf(f.x); o.y = f2bf(f.y); o.z = f2bf(f.z); o.w = f2bf(f.w);
  dst[c] = o;
}

// ============ 8-phase 256x256 GEMM: C[M,N] = A[M,K] * Bt[N,K]^T (bf16, fp32 acc) ============
// XCD M-slab mapping: xcd = bid%8 owns m-tiles [xcd*16, xcd*16+16), n-fastest -> A fetched
// once/L3 per m-tile, B L2-resident per XCD.
// EPI 0: LDS-staged coalesced epilogue, 16B (bf16x8) chunks.
// EPI 1: fp32 + bias, window-unpartition row permute (direct stores).
template<int EPI>
__global__ __launch_bounds__(512, 2)
void sab_gemm8_kernel(const u16* __restrict__ A, const u16* __restrict__ Bt,
                      u16* __restrict__ outB, u16* __restrict__ vTp,
                      float* __restrict__ outF, const float* __restrict__ bias,
                      const int K)
{
  __shared__ __align__(16) u16 lds[2][2][2][8192];   // [buf][A=0/B=1][half][row*64+col]
  const int tid = threadIdx.x;
  const int lane = tid & 63, wid = tid >> 6;
  const int wr = wid >> 2, wc = wid & 3;             // 2M x 4N wave grid
  const int lr = lane & 15, lg = lane >> 4;

  // XCD slab: m = xcd*16 + local/NY, n = local%NY  (NX=128, nwg%8==0)
  const int NY = gridDim.y;
  const int bid0 = blockIdx.y * gridDim.x + blockIdx.x;
  const int xcd = bid0 & 7, local = bid0 >> 3;
  const long m0 = (long)(xcd * 16 + local / NY) * 256;
  const long n0 = (long)(local % NY) * 256;

  // per-lane pre-swizzled global staging bases (inverse swizzle on source)
  const int swz = ((lane & 7) ^ (lane >> 3)) << 3;   // element offset
  const u16* Agl = A  + (m0 + wid * 8 + (lane >> 3)) * (long)K + swz;
  const u16* Bgl = Bt + (n0 + wid * 8 + (lane >> 3)) * (long)K + swz;

  f32x4 acc[8][4];
#pragma unroll
  for (int a = 0; a < 8; ++a)
#pragma unroll
    for (int b = 0; b < 4; ++b) acc[a][b] = (f32x4){0.f, 0.f, 0.f, 0.f};

  auto stage = [&](int buf, int mat, int half, int rb, int kt) {
    const u16* g = (mat ? Bgl : Agl) + (half * 128 + rb) * (long)K + kt;
    gload16(g, &lds[buf][mat][half][(rb + wid * 8) * 64]);
  };
  auto rdA4 = [&](int buf, int q, bf16x8 (&out)[4][2]) {
#pragma unroll
    for (int m2 = 0; m2 < 4; ++m2)
#pragma unroll
      for (int kc = 0; kc < 2; ++kc)
        out[m2][kc] = *reinterpret_cast<const bf16x8*>(
          &lds[buf][0][wr][(q * 64 + m2 * 16 + lr) * 64 + ((kc * 32 + lg * 8) ^ ((lr & 7) << 3))]);
  };
  auto rdB2 = [&](int buf, int q, bf16x8 (&out)[2][2]) {
#pragma unroll
    for (int n2 = 0; n2 < 2; ++n2)
#pragma unroll
      for (int kc = 0; kc < 2; ++kc)
        out[n2][kc] = *reinterpret_cast<const bf16x8*>(
          &lds[buf][1][wc >> 1][((wc & 1) * 64 + q * 32 + n2 * 16 + lr) * 64 + ((kc * 32 + lg * 8) ^ ((lr & 7) << 3))]);
  };
  auto mma16 = [&](bf16x8 (&a)[4][2], bf16x8 (&b)[2][2], int mq, int nq) {
    __builtin_amdgcn_s_setprio(1);
#pragma unroll
    for (int kc = 0; kc < 2; ++kc)
#pragma unroll
      for (int m2 = 0; m2 < 4; ++m2)
#pragma unroll
        for (int n2 = 0; n2 < 2; ++n2)
          acc[mq * 4 + m2][nq * 2 + n2] = __builtin_amdgcn_mfma_f32_16x16x32_bf16(
              a[m2][kc], b[n2][kc], acc[mq * 4 + m2][nq * 2 + n2], 0, 0, 0);
    __builtin_amdgcn_s_setprio(0);
  };

  // ---- prologue: t0 all 8 units, t1 first 6 units; drain t0; barrier ----
  stage(0,0,0,0,0);  stage(0,0,1,0,0);  stage(0,1,0,0,0);  stage(0,1,1,0,0);
  stage(0,1,0,64,0); stage(0,1,1,64,0); stage(0,0,0,64,0); stage(0,0,1,64,0);
  stage(1,0,0,0,64); stage(1,0,1,0,64); stage(1,1,0,0,64); stage(1,1,1,0,64);
  stage(1,1,0,64,64); stage(1,1,1,64,64);
  VM6; PH_BAR;

  bf16x8 af[4][2], b0[2][2], b1[2][2];

  for (int kt = 0; kt < K; kt += 128) {
    const int k2 = kt + 128, k3 = kt + 192;
    const bool s2 = k2 < K, s3 = k3 < K;
    // P1: Q00 buf0; stage t1.A rb64 units (freed by prev P7)
    rdA4(0, 0, af); rdB2(0, 0, b0);
    stage(1,0,0,64, kt + 64); stage(1,0,1,64, kt + 64);
    PH_BAR; LGKM0; mma16(af, b0, 0, 0); PH_BAR;
    // P2: Q01; stage t2.A rb0 units (freed by P1)
    rdB2(0, 1, b1);
    if (s2) { stage(0,0,0,0, k2); stage(0,0,1,0, k2); }
    PH_BAR; LGKM0; mma16(af, b1, 0, 1); PH_BAR;
    // P3: Q10; stage t2.B rb0 (all B-buf0 freed by P2)
    rdA4(0, 1, af);
    if (s2) { stage(0,1,0,0, k2); stage(0,1,1,0, k2); }
    PH_BAR; LGKM0; mma16(af, b0, 1, 0); PH_BAR;
    // P4: Q11; stage t2.B rb64; drain to 6 (t1 fully landed)
    if (s2) { stage(0,1,0,64, k2); stage(0,1,1,64, k2); }
    PH_BAR; mma16(af, b1, 1, 1); VM6; PH_BAR;
    // P5: Q00 buf1; stage t2.A rb64 (freed by P3)
    rdA4(1, 0, af); rdB2(1, 0, b0);
    if (s2) { stage(0,0,0,64, k2); stage(0,0,1,64, k2); }
    PH_BAR; LGKM0; mma16(af, b0, 0, 0); PH_BAR;
    // P6: Q01; stage t3.A rb0 (freed by P5)
    rdB2(1, 1, b1);
    if (s3) { stage(1,0,0,0, k3); stage(1,0,1,0, k3); }
    PH_BAR; LGKM0; mma16(af, b1, 0, 1); PH_BAR;
    // P7: Q10; stage t3.B rb0 (all B-buf1 freed by P6)
    rdA4(1, 1, af);
    if (s3) { stage(1,1,0,0, k3); stage(1,1,1,0, k3); }
    PH_BAR; LGKM0; mma16(af, b0, 1, 0); PH_BAR;
    // P8: Q11; stage t3.B rb64; drain to 6 (t2 fully landed)
    if (s3) { stage(1,1,0,64, k3); stage(1,1,1,64, k3); }
    PH_BAR; mma16(af, b1, 1, 1); VM6; PH_BAR;
  }

  // ---- drain all staging loads, then reuse the 128-KB LDS for the epilogue ----
  VM0;
  __syncthreads();
  u16* cl = &lds[0][0][0][0];                        // 65536 u16 = 256x256 bf16

  if (EPI == 0) {
    if (n0 < 1536) {
      // q/k region: row-major [256][256] tile, then coalesced 16B stores (ld 1536)
#pragma unroll
      for (int mt = 0; mt < 8; ++mt)
#pragma unroll
        for (int nt = 0; nt < 4; ++nt) {
          const int col = wc * 64 + nt * 16 + lr;
          const int row0 = wr * 128 + mt * 16 + lg * 4;
#pragma unroll
          for (int r = 0; r < 4; ++r)
            cl[(row0 + r) * 256 + col] = f2bf(acc[mt][nt][r]);
        }
      __syncthreads();
#pragma unroll
      for (int s = 0; s < 16; ++s) {
        const int c = s * 512 + tid;
        const int row = c >> 5, ch = c & 31;         // 32 chunks x 8 elems = 256 cols
        *reinterpret_cast<bf16x8*>(&outB[(m0 + row) * 1536 + n0 + ch * 8]) =
            *reinterpret_cast<const bf16x8*>(&cl[row * 256 + ch * 8]);
      }
    } else {
      // v region: transposed tile cl[d][row], b64-packed writes, coalesced 16B vT stores
#pragma unroll
      for (int mt = 0; mt < 8; ++mt)
#pragma unroll
        for (int nt = 0; nt < 4; ++nt) {
          const int col = wc * 64 + nt * 16 + lr;
          const int row0 = wr * 128 + mt * 16 + lg * 4;
          ushort4 o;
          o.x = f2bf(acc[mt][nt][0]); o.y = f2bf(acc[mt][nt][1]);
          o.z = f2bf(acc[mt][nt][2]); o.w = f2bf(acc[mt][nt][3]);
          *reinterpret_cast<ushort4*>(&cl[col * 256 + row0]) = o;   // 4 elems, intended
        }
      __syncthreads();
#pragma unroll
      for (int s = 0; s < 16; ++s) {
        const int c = s * 512 + tid;
        const int d = c >> 5, ch = c & 31;
        *reinterpret_cast<bf16x8*>(&vTp[(n0 - 1536 + d) * 32768L + m0 + ch * 8]) =
            *reinterpret_cast<const bf16x8*>(&cl[d * 256 + ch * 8]);
      }
    }
  } else {
#pragma unroll
    for (int mt = 0; mt < 8; ++mt)
#pragma unroll
      for (int nt = 0; nt < 4; ++nt) {
        const long col = n0 + wc * 64 + nt * 16 + lr;
        const float bv = bias[col];
        const long row0 = m0 + wr * 128 + mt * 16 + lg * 4;
#pragma unroll
        for (int r = 0; r < 4; ++r) {
          const int rr = (int)(row0 + r);
          const int w = rr >> 8, tt = rr & 255;
          const long xrow = (long)(w >> 4) * 4096 + (((w >> 2) & 3) * 16 + (tt >> 4)) * 64 + (w & 3) * 16 + (tt & 15);
          outF[xrow * 768 + col] = acc[mt][nt][r] + bv;
        }
      }
  }
}

// ---------------- fused windowed attention: one block per (window, head) ----------------
// qk layout: [32768][1536]: q at col 0, k at 768; head h owns cols h*64..h*64+63.
// vT layout: [768][32768]. Latency/VALU-bound at 2 blocks/CU (R6: Occ 21%, VALUBusy 33%).
// bounds (256,3): 3 blocks/CU (LDS 25.6KB x 3 = 77KB; VGPR cap 170 > ~128 actual — no squeeze).
// NOTE: (256,4) failed post-timing re-validation (R7, nondeterministic) — exact-128 VGPR
// squeeze regime unvalidated; (256,3) passed full validation+replays in R5.
__global__ __launch_bounds__(256, 3)
void sab_attn_kernel(const u16* __restrict__ qk, const u16* __restrict__ vT,
                     const float* __restrict__ rph, const float* __restrict__ rpw,
                     u16* __restrict__ oatt)
{
  __shared__ __align__(16) u16 relh_s[256 * 16];     // bias_h[x][k]  (bf16)
  __shared__ __align__(16) u16 relw_s[256 * 16];     // bias_w[x][l]
  __shared__ __align__(16) u16 Sbuf[4][16 * 72];     // per-wave P tile, one 16-row mt-block

  const int blk0 = blockIdx.x;
  const int blk = (blk0 & 7) * 192 + (blk0 >> 3);    // XCD slab: 16 windows x 12 heads per XCD
  const int w = blk / 12, h = blk % 12;
  const long qbase = (long)w * 256;
  const int tid = threadIdx.x, lane = tid & 63, wid = tid >> 6;
  const int lr = lane & 15, lg = lane >> 4;

  const u16* Qp = qk + (long)h * 64;
  const u16* Kp = qk + 768 + (long)h * 64;
  const u16* Vt = vT + (long)h * 64 * 32768 + w * 256;

  // ---- phase 0: decomposed rel-pos tables via MFMA ----
#pragma unroll
  for (int ii = 0; ii < 4; ++ii) {
    const int i = wid * 4 + ii;
    f32x4 acc = (f32x4){0.f, 0.f, 0.f, 0.f};
#pragma unroll
    for (int kc = 0; kc < 2; ++kc) {
      bf16x8 a = *reinterpret_cast<const bf16x8*>(&Qp[(qbase + i * 16 + lr) * 1536 + kc * 32 + lg * 8]);
      const float* bp = rph + (i - lr + 15) * 64 + kc * 32 + lg * 8;
      bf16x8 b;
#pragma unroll
      for (int e = 0; e < 8; ++e) b[e] = (short)f2bf(bp[e]);
      acc = __builtin_amdgcn_mfma_f32_16x16x32_bf16(a, b, acc, 0, 0, 0);
    }
#pragma unroll
    for (int r = 0; r < 4; ++r)
      relh_s[(i * 16 + lg * 4 + r) * 16 + lr] = f2bf(acc[r]);
  }
#pragma unroll
  for (int jj = 0; jj < 4; ++jj) {
    const int j = wid * 4 + jj;
    f32x4 acc = (f32x4){0.f, 0.f, 0.f, 0.f};
#pragma unroll
    for (int kc = 0; kc < 2; ++kc) {
      bf16x8 a = *reinterpret_cast<const bf16x8*>(&Qp[(qbase + lr * 16 + j) * 1536 + kc * 32 + lg * 8]);
      const float* bp = rpw + (j - lr + 15) * 64 + kc * 32 + lg * 8;
      bf16x8 b;
#pragma unroll
      for (int e = 0; e < 8; ++e) b[e] = (short)f2bf(bp[e]);
      acc = __builtin_amdgcn_mfma_f32_16x16x32_bf16(a, b, acc, 0, 0, 0);
    }
#pragma unroll
    for (int r = 0; r < 4; ++r)
      relw_s[((lg * 4 + r) * 16 + j) * 16 + lr] = f2bf(acc[r]);
  }
  __syncthreads();                          // the ONLY block-wide barrier

  bf16x8 qa[4][2];
#pragma unroll
  for (int mt = 0; mt < 4; ++mt)
#pragma unroll
    for (int kc = 0; kc < 2; ++kc)
      qa[mt][kc] = *reinterpret_cast<const bf16x8*>(&Qp[(qbase + wid * 64 + mt * 16 + lr) * 1536 + kc * 32 + lg * 8]);

  float rw[4][4];
#pragma unroll
  for (int mt = 0; mt < 4; ++mt)
#pragma unroll
    for (int r = 0; r < 4; ++r)
      rw[mt][r] = bf2f(relw_s[(wid * 64 + mt * 16 + lg * 4 + r) * 16 + lr]);

  float mrun[4][4], lrun[4][4];
  f32x4 oacc[4][4];
#pragma unroll
  for (int mt = 0; mt < 4; ++mt)
#pragma unroll
    for (int r = 0; r < 4; ++r) { mrun[mt][r] = -1e30f; lrun[mt][r] = 0.f; }
#pragma unroll
  for (int mt = 0; mt < 4; ++mt)
#pragma unroll
    for (int nt = 0; nt < 4; ++nt) oacc[mt][nt] = (f32x4){0.f, 0.f, 0.f, 0.f};

  u16* sb = &Sbuf[wid][0];

  for (int kb = 0; kb < 4; ++kb) {
    bf16x8 kf[4][2], vf[4][2];
#pragma unroll
    for (int nt = 0; nt < 4; ++nt)
#pragma unroll
      for (int kc = 0; kc < 2; ++kc) {
        kf[nt][kc] = *reinterpret_cast<const bf16x8*>(&Kp[(qbase + kb * 64 + nt * 16 + lr) * 1536 + kc * 32 + lg * 8]);
        vf[nt][kc] = *reinterpret_cast<const bf16x8*>(&Vt[(nt * 16 + lr) * 32768L + kb * 64 + kc * 32 + lg * 8]);
      }

#pragma unroll
    for (int mt = 0; mt < 4; ++mt) {
      f32x4 sn[4];
#pragma unroll
      for (int nt = 0; nt < 4; ++nt) {
        f32x4 t = (f32x4){0.f, 0.f, 0.f, 0.f};
#pragma unroll
        for (int kc = 0; kc < 2; ++kc)
          t = __builtin_amdgcn_mfma_f32_16x16x32_bf16(qa[mt][kc], kf[nt][kc], t, 0, 0, 0);
        sn[nt] = t;
      }
#pragma unroll
      for (int r = 0; r < 4; ++r) {
        const int x = wid * 64 + mt * 16 + lg * 4 + r;
        float sv[4];
#pragma unroll
        for (int nt = 0; nt < 4; ++nt)
          sv[nt] = sn[nt][r] * 0.125f + bf2f(relh_s[x * 16 + kb * 4 + nt]) + rw[mt][r];
        float rmax = fmaxf(fmaxf(sv[0], sv[1]), fmaxf(sv[2], sv[3]));
        rmax = fmaxf(rmax, __shfl_xor(rmax, 1));
        rmax = fmaxf(rmax, __shfl_xor(rmax, 2));
        rmax = fmaxf(rmax, __shfl_xor(rmax, 4));
        rmax = fmaxf(rmax, __shfl_xor(rmax, 8));
        const float mnew = fmaxf(mrun[mt][r], rmax);
        const float sf = __expf(mrun[mt][r] - mnew);
        mrun[mt][r] = mnew;
        float rsum = 0.f;
#pragma unroll
        for (int nt = 0; nt < 4; ++nt) { const float p = __expf(sv[nt] - mnew); sv[nt] = p; rsum += p; }
        rsum += __shfl_xor(rsum, 1);
        rsum += __shfl_xor(rsum, 2);
        rsum += __shfl_xor(rsum, 4);
        rsum += __shfl_xor(rsum, 8);
        lrun[mt][r] = lrun[mt][r] * sf + rsum;
#pragma unroll
        for (int nt = 0; nt < 4; ++nt) oacc[mt][nt][r] *= sf;
        const int rowl = lg * 4 + r;               // row within this 16-row mt-block
#pragma unroll
        for (int nt = 0; nt < 4; ++nt) sb[rowl * 72 + nt * 16 + lr] = f2bf(sv[nt]);
      }
      // ---- PV for this mt-block (same-wave LDS write->read; compiler inserts lgkmcnt) ----
#pragma unroll
      for (int kc = 0; kc < 2; ++kc) {
        bf16x8 pa = *reinterpret_cast<const bf16x8*>(&sb[lr * 72 + kc * 32 + lg * 8]);
#pragma unroll
        for (int nt = 0; nt < 4; ++nt)
          oacc[mt][nt] = __builtin_amdgcn_mfma_f32_16x16x32_bf16(pa, vf[nt][kc], oacc[mt][nt], 0, 0, 0);
      }
    }
  }

  // ---- epilogue: O / l -> oatt[row][h*64+d] (bf16) ----
#pragma unroll
  for (int mt = 0; mt < 4; ++mt)
#pragma unroll
    for (int r = 0; r < 4; ++r) {
      const float inv = 1.f / lrun[mt][r];
      const long row = qbase + wid * 64 + mt * 16 + lg * 4 + r;
#pragma unroll
      for (int nt = 0; nt < 4; ++nt)
        oatt[row * 768 + h * 64 + nt * 16 + lr] = f2bf(oacc[mt][nt][r] * inv);
    }
}

extern "C" void kernel_launch(void* const* d_in, const int* in_sizes, int n_in,
                              void* d_out, int out_size, void* d_ws, size_t ws_size,
                              hipStream_t stream) {
  (void)in_sizes; (void)n_in; (void)out_size; (void)ws_size;
  const float* x     = (const float*)d_in[0];
  const float* w_qkv = (const float*)d_in[1];
  const float* w_out = (const float*)d_in[2];
  const float* b_out = (const float*)d_in[3];
  const float* rph   = (const float*)d_in[4];
  const float* rpw   = (const float*)d_in[5];
  float* out = (float*)d_out;

  char* ws = (char*)d_ws;
  u16* qk    = (u16*)ws;                              // 32768*1536 bf16 = 100.7 MB (q,k row-major)
  u16* vT    = (u16*)(ws + 100663296L);               // 768*32768  bf16 =  50.3 MB (v transposed)
  u16* xw    = (u16*)(ws + 150994944L);               // 32768*768  bf16 =  50.3 MB (reused as oatt)
  u16* wqkvb = (u16*)(ws + 201326592L);               // 2304*768 bf16
  u16* woutb = (u16*)(ws + 204865536L);               //  768*768 bf16; total 206,045,184 B
  u16* oatt  = xw;                                    // xw is dead after gemm1

  sab_cvt_kernel<<<dim3(1728), dim3(256), 0, stream>>>(w_qkv, wqkvb, 442368);
  sab_cvt_kernel<<<dim3(576), dim3(256), 0, stream>>>(w_out, woutb, 147456);
  sab_xw_kernel<<<dim3(32768), dim3(192), 0, stream>>>(x, xw);
  sab_gemm8_kernel<0><<<dim3(128, 9), dim3(512), 0, stream>>>(xw, wqkvb, qk, vT, nullptr, nullptr, 768);
  sab_attn_kernel<<<dim3(1536), dim3(256), 0, stream>>>(qk, vT, rph, rpw, oatt);
  sab_gemm8_kernel<1><<<dim3(128, 3), dim3(512), 0, stream>>>(oatt, woutb, nullptr, nullptr, out, b_out, 768);
}

// Round 11
// 356.288 us; speedup vs baseline: 1.4197x; 1.4197x over previous
//
#include <hip/hip_runtime.h>

typedef __attribute__((ext_vector_type(8))) short bf16x8;
typedef __attribute__((ext_vector_type(4))) float f32x4;
typedef unsigned short u16;

__device__ __forceinline__ u16 f2bf(float f) {
  union { float f; unsigned u; } v; v.f = f;
  unsigned r = v.u + 0x7fffu + ((v.u >> 16) & 1u);   // RNE
  return (u16)(r >> 16);
}
__device__ __forceinline__ float bf2f(u16 u) {
  union { unsigned u; float f; } v; v.u = ((unsigned)u) << 16;
  return v.f;
}
__device__ __forceinline__ void gload16(const void* g, void* l) {
  __builtin_amdgcn_global_load_lds((const __attribute__((address_space(1))) void*)g,
                                   (__attribute__((address_space(3))) void*)l, 16, 0, 0);
}

#define PH_BAR __builtin_amdgcn_s_barrier()
#define LGKM0  asm volatile("s_waitcnt lgkmcnt(0)" ::: "memory")
#define VM6    asm volatile("s_waitcnt vmcnt(6)" ::: "memory")
#define VM0    asm volatile("s_waitcnt vmcnt(0)" ::: "memory")

// ---------------- fp32 -> bf16 converter (4 elems/thread) ----------------
__global__ void sab_cvt_kernel(const float* __restrict__ src, u16* __restrict__ dst, int n4) {
  int i = blockIdx.x * blockDim.x + threadIdx.x;
  if (i >= n4) return;
  float4 f = reinterpret_cast<const float4*>(src)[i];
  ushort4 o; o.x = f2bf(f.x); o.y = f2bf(f.y); o.z = f2bf(f.z); o.w = f2bf(f.w);
  reinterpret_cast<ushort4*>(dst)[i] = o;
}

// ------------- window partition + convert: xw[r][c] = x[xrow(r)][c] -------------
__global__ void sab_xw_kernel(const float* __restrict__ x, u16* __restrict__ xw) {
  const int r = blockIdx.x;                 // 0..32767 (window-token row)
  const int w = r >> 8, tt = r & 255;
  const int b = w >> 4, h1 = (w >> 2) & 3, w1 = w & 3;
  const int i = tt >> 4, j = tt & 15;
  const long xrow = (long)b * 4096 + (h1 * 16 + i) * 64 + w1 * 16 + j;
  const float4* src = reinterpret_cast<const float4*>(x + xrow * 768);
  ushort4* dst = reinterpret_cast<ushort4*>(xw + (long)r * 768);
  const int c = threadIdx.x;                // 0..191, 192*4 = 768
  float4 f = src[c];
  ushort4 o; o.x = f2bf(f.x); o.y = f2bf(f.y); o.z = f2bf(f.z); o.w = f2bf(f.w);
  dst[c] = o;
}

// ============ 8-phase 256x256 GEMM: C[M,N] = A[M,K] * Bt[N,K]^T (bf16, fp32 acc) ============
// (unchanged — passed R5/R6/R8 validation+replays)
template<int EPI>
__global__ __launch_bounds__(512, 2)
void sab_gemm8_kernel(const u16* __restrict__ A, const u16* __restrict__ Bt,
                      u16* __restrict__ outB, u16* __restrict__ vTp,
                      float* __restrict__ outF, const float* __restrict__ bias,
                      const int K)
{
  __shared__ __align__(16) u16 lds[2][2][2][8192];   // [buf][A=0/B=1][half][row*64+col]
  const int tid = threadIdx.x;
  const int lane = tid & 63, wid = tid >> 6;
  const int wr = wid >> 2, wc = wid & 3;             // 2M x 4N wave grid
  const int lr = lane & 15, lg = lane >> 4;

  // XCD slab: m = xcd*16 + local/NY, n = local%NY  (NX=128, nwg%8==0)
  const int NY = gridDim.y;
  const int bid0 = blockIdx.y * gridDim.x + blockIdx.x;
  const int xcd = bid0 & 7, local = bid0 >> 3;
  const long m0 = (long)(xcd * 16 + local / NY) * 256;
  const long n0 = (long)(local % NY) * 256;

  // per-lane pre-swizzled global staging bases (inverse swizzle on source)
  const int swz = ((lane & 7) ^ (lane >> 3)) << 3;   // element offset
  const u16* Agl = A  + (m0 + wid * 8 + (lane >> 3)) * (long)K + swz;
  const u16* Bgl = Bt + (n0 + wid * 8 + (lane >> 3)) * (long)K + swz;

  f32x4 acc[8][4];
#pragma unroll
  for (int a = 0; a < 8; ++a)
#pragma unroll
    for (int b = 0; b < 4; ++b) acc[a][b] = (f32x4){0.f, 0.f, 0.f, 0.f};

  auto stage = [&](int buf, int mat, int half, int rb, int kt) {
    const u16* g = (mat ? Bgl : Agl) + (half * 128 + rb) * (long)K + kt;
    gload16(g, &lds[buf][mat][half][(rb + wid * 8) * 64]);
  };
  auto rdA4 = [&](int buf, int q, bf16x8 (&out)[4][2]) {
#pragma unroll
    for (int m2 = 0; m2 < 4; ++m2)
#pragma unroll
      for (int kc = 0; kc < 2; ++kc)
        out[m2][kc] = *reinterpret_cast<const bf16x8*>(
          &lds[buf][0][wr][(q * 64 + m2 * 16 + lr) * 64 + ((kc * 32 + lg * 8) ^ ((lr & 7) << 3))]);
  };
  auto rdB2 = [&](int buf, int q, bf16x8 (&out)[2][2]) {
#pragma unroll
    for (int n2 = 0; n2 < 2; ++n2)
#pragma unroll
      for (int kc = 0; kc < 2; ++kc)
        out[n2][kc] = *reinterpret_cast<const bf16x8*>(
          &lds[buf][1][wc >> 1][((wc & 1) * 64 + q * 32 + n2 * 16 + lr) * 64 + ((kc * 32 + lg * 8) ^ ((lr & 7) << 3))]);
  };
  auto mma16 = [&](bf16x8 (&a)[4][2], bf16x8 (&b)[2][2], int mq, int nq) {
    __builtin_amdgcn_s_setprio(1);
#pragma unroll
    for (int kc = 0; kc < 2; ++kc)
#pragma unroll
      for (int m2 = 0; m2 < 4; ++m2)
#pragma unroll
        for (int n2 = 0; n2 < 2; ++n2)
          acc[mq * 4 + m2][nq * 2 + n2] = __builtin_amdgcn_mfma_f32_16x16x32_bf16(
              a[m2][kc], b[n2][kc], acc[mq * 4 + m2][nq * 2 + n2], 0, 0, 0);
    __builtin_amdgcn_s_setprio(0);
  };

  // ---- prologue: t0 all 8 units, t1 first 6 units; drain t0; barrier ----
  stage(0,0,0,0,0);  stage(0,0,1,0,0);  stage(0,1,0,0,0);  stage(0,1,1,0,0);
  stage(0,1,0,64,0); stage(0,1,1,64,0); stage(0,0,0,64,0); stage(0,0,1,64,0);
  stage(1,0,0,0,64); stage(1,0,1,0,64); stage(1,1,0,0,64); stage(1,1,1,0,64);
  stage(1,1,0,64,64); stage(1,1,1,64,64);
  VM6; PH_BAR;

  bf16x8 af[4][2], b0[2][2], b1[2][2];

  for (int kt = 0; kt < K; kt += 128) {
    const int k2 = kt + 128, k3 = kt + 192;
    const bool s2 = k2 < K, s3 = k3 < K;
    // P1: Q00 buf0; stage t1.A rb64 units (freed by prev P7)
    rdA4(0, 0, af); rdB2(0, 0, b0);
    stage(1,0,0,64, kt + 64); stage(1,0,1,64, kt + 64);
    PH_BAR; LGKM0; mma16(af, b0, 0, 0); PH_BAR;
    // P2: Q01; stage t2.A rb0 units (freed by P1)
    rdB2(0, 1, b1);
    if (s2) { stage(0,0,0,0, k2); stage(0,0,1,0, k2); }
    PH_BAR; LGKM0; mma16(af, b1, 0, 1); PH_BAR;
    // P3: Q10; stage t2.B rb0 (all B-buf0 freed by P2)
    rdA4(0, 1, af);
    if (s2) { stage(0,1,0,0, k2); stage(0,1,1,0, k2); }
    PH_BAR; LGKM0; mma16(af, b0, 1, 0); PH_BAR;
    // P4: Q11; stage t2.B rb64; drain to 6 (t1 fully landed)
    if (s2) { stage(0,1,0,64, k2); stage(0,1,1,64, k2); }
    PH_BAR; mma16(af, b1, 1, 1); VM6; PH_BAR;
    // P5: Q00 buf1; stage t2.A rb64 (freed by P3)
    rdA4(1, 0, af); rdB2(1, 0, b0);
    if (s2) { stage(0,0,0,64, k2); stage(0,0,1,64, k2); }
    PH_BAR; LGKM0; mma16(af, b0, 0, 0); PH_BAR;
    // P6: Q01; stage t3.A rb0 (freed by P5)
    rdB2(1, 1, b1);
    if (s3) { stage(1,0,0,0, k3); stage(1,0,1,0, k3); }
    PH_BAR; LGKM0; mma16(af, b1, 0, 1); PH_BAR;
    // P7: Q10; stage t3.B rb0 (all B-buf1 freed by P6)
    rdA4(1, 1, af);
    if (s3) { stage(1,1,0,0, k3); stage(1,1,1,0, k3); }
    PH_BAR; LGKM0; mma16(af, b0, 1, 0); PH_BAR;
    // P8: Q11; stage t3.B rb64; drain to 6 (t2 fully landed)
    if (s3) { stage(1,1,0,64, k3); stage(1,1,1,64, k3); }
    PH_BAR; mma16(af, b1, 1, 1); VM6; PH_BAR;
  }

  // ---- drain all staging loads, then reuse the 128-KB LDS for the epilogue ----
  VM0;
  __syncthreads();
  u16* cl = &lds[0][0][0][0];                        // 65536 u16 = 256x256 bf16

  if (EPI == 0) {
    if (n0 < 1536) {
      // q/k region: row-major [256][256] tile, then coalesced 16B stores (ld 1536)
#pragma unroll
      for (int mt = 0; mt < 8; ++mt)
#pragma unroll
        for (int nt = 0; nt < 4; ++nt) {
          const int col = wc * 64 + nt * 16 + lr;
          const int row0 = wr * 128 + mt * 16 + lg * 4;
#pragma unroll
          for (int r = 0; r < 4; ++r)
            cl[(row0 + r) * 256 + col] = f2bf(acc[mt][nt][r]);
        }
      __syncthreads();
#pragma unroll
      for (int s = 0; s < 16; ++s) {
        const int c = s * 512 + tid;
        const int row = c >> 5, ch = c & 31;         // 32 chunks x 8 elems = 256 cols
        *reinterpret_cast<bf16x8*>(&outB[(m0 + row) * 1536 + n0 + ch * 8]) =
            *reinterpret_cast<const bf16x8*>(&cl[row * 256 + ch * 8]);
      }
    } else {
      // v region: transposed tile cl[d][row], b64-packed writes, coalesced 16B vT stores
#pragma unroll
      for (int mt = 0; mt < 8; ++mt)
#pragma unroll
        for (int nt = 0; nt < 4; ++nt) {
          const int col = wc * 64 + nt * 16 + lr;
          const int row0 = wr * 128 + mt * 16 + lg * 4;
          ushort4 o;
          o.x = f2bf(acc[mt][nt][0]); o.y = f2bf(acc[mt][nt][1]);
          o.z = f2bf(acc[mt][nt][2]); o.w = f2bf(acc[mt][nt][3]);
          *reinterpret_cast<ushort4*>(&cl[col * 256 + row0]) = o;   // 4 elems, intended
        }
      __syncthreads();
#pragma unroll
      for (int s = 0; s < 16; ++s) {
        const int c = s * 512 + tid;
        const int d = c >> 5, ch = c & 31;
        *reinterpret_cast<bf16x8*>(&vTp[(n0 - 1536 + d) * 32768L + m0 + ch * 8]) =
            *reinterpret_cast<const bf16x8*>(&cl[d * 256 + ch * 8]);
      }
    }
  } else {
#pragma unroll
    for (int mt = 0; mt < 8; ++mt)
#pragma unroll
      for (int nt = 0; nt < 4; ++nt) {
        const long col = n0 + wc * 64 + nt * 16 + lr;
        const float bv = bias[col];
        const long row0 = m0 + wr * 128 + mt * 16 + lg * 4;
#pragma unroll
        for (int r = 0; r < 4; ++r) {
          const int rr = (int)(row0 + r);
          const int w = rr >> 8, tt = rr & 255;
          const long xrow = (long)(w >> 4) * 4096 + (((w >> 2) & 3) * 16 + (tt >> 4)) * 64 + (w & 3) * 16 + (tt & 15);
          outF[xrow * 768 + col] = acc[mt][nt][r] + bv;
        }
      }
  }
}

// ---------------- fused windowed attention: one block per (window, head) ----------------
// R6-family body (the ONLY configuration that passes replay validation: R5/R6/R8).
// (256,2), no K/V LDS staging, no raw barriers. Change vs R6: softmax SUM-reduce deferred —
// lrun holds per-lane partials (rescale is linear; sf is lane-uniform after max broadcast),
// one 4-shfl butterfly in the epilogue instead of per-kb (saves 192 dependent shfls/wave).
__global__ __launch_bounds__(256, 2)
void sab_attn_kernel(const u16* __restrict__ qk, const u16* __restrict__ vT,
                     const float* __restrict__ rph, const float* __restrict__ rpw,
                     u16* __restrict__ oatt)
{
  __shared__ __align__(16) u16 relh_s[256 * 16];     // bias_h[x][k]  (bf16)
  __shared__ __align__(16) u16 relw_s[256 * 16];     // bias_w[x][l]
  __shared__ __align__(16) u16 Sbuf[4][16 * 72];     // per-wave P tile, one 16-row mt-block

  const int blk0 = blockIdx.x;
  const int blk = (blk0 & 7) * 192 + (blk0 >> 3);    // XCD slab: 16 windows x 12 heads per XCD
  const int w = blk / 12, h = blk % 12;
  const long qbase = (long)w * 256;
  const int tid = threadIdx.x, lane = tid & 63, wid = tid >> 6;
  const int lr = lane & 15, lg = lane >> 4;

  const u16* Qp = qk + (long)h * 64;
  const u16* Kp = qk + 768 + (long)h * 64;
  const u16* Vt = vT + (long)h * 64 * 32768 + w * 256;

  // ---- phase 0: decomposed rel-pos tables via MFMA ----
#pragma unroll
  for (int ii = 0; ii < 4; ++ii) {
    const int i = wid * 4 + ii;
    f32x4 acc = (f32x4){0.f, 0.f, 0.f, 0.f};
#pragma unroll
    for (int kc = 0; kc < 2; ++kc) {
      bf16x8 a = *reinterpret_cast<const bf16x8*>(&Qp[(qbase + i * 16 + lr) * 1536 + kc * 32 + lg * 8]);
      const float* bp = rph + (i - lr + 15) * 64 + kc * 32 + lg * 8;
      bf16x8 b;
#pragma unroll
      for (int e = 0; e < 8; ++e) b[e] = (short)f2bf(bp[e]);
      acc = __builtin_amdgcn_mfma_f32_16x16x32_bf16(a, b, acc, 0, 0, 0);
    }
#pragma unroll
    for (int r = 0; r < 4; ++r)
      relh_s[(i * 16 + lg * 4 + r) * 16 + lr] = f2bf(acc[r]);
  }
#pragma unroll
  for (int jj = 0; jj < 4; ++jj) {
    const int j = wid * 4 + jj;
    f32x4 acc = (f32x4){0.f, 0.f, 0.f, 0.f};
#pragma unroll
    for (int kc = 0; kc < 2; ++kc) {
      bf16x8 a = *reinterpret_cast<const bf16x8*>(&Qp[(qbase + lr * 16 + j) * 1536 + kc * 32 + lg * 8]);
      const float* bp = rpw + (j - lr + 15) * 64 + kc * 32 + lg * 8;
      bf16x8 b;
#pragma unroll
      for (int e = 0; e < 8; ++e) b[e] = (short)f2bf(bp[e]);
      acc = __builtin_amdgcn_mfma_f32_16x16x32_bf16(a, b, acc, 0, 0, 0);
    }
#pragma unroll
    for (int r = 0; r < 4; ++r)
      relw_s[((lg * 4 + r) * 16 + j) * 16 + lr] = f2bf(acc[r]);
  }
  __syncthreads();                          // the ONLY block-wide barrier

  bf16x8 qa[4][2];
#pragma unroll
  for (int mt = 0; mt < 4; ++mt)
#pragma unroll
    for (int kc = 0; kc < 2; ++kc)
      qa[mt][kc] = *reinterpret_cast<const bf16x8*>(&Qp[(qbase + wid * 64 + mt * 16 + lr) * 1536 + kc * 32 + lg * 8]);

  float rw[4][4];
#pragma unroll
  for (int mt = 0; mt < 4; ++mt)
#pragma unroll
    for (int r = 0; r < 4; ++r)
      rw[mt][r] = bf2f(relw_s[(wid * 64 + mt * 16 + lg * 4 + r) * 16 + lr]);

  float mrun[4][4], lrun[4][4];
  f32x4 oacc[4][4];
#pragma unroll
  for (int mt = 0; mt < 4; ++mt)
#pragma unroll
    for (int r = 0; r < 4; ++r) { mrun[mt][r] = -1e30f; lrun[mt][r] = 0.f; }
#pragma unroll
  for (int mt = 0; mt < 4; ++mt)
#pragma unroll
    for (int nt = 0; nt < 4; ++nt) oacc[mt][nt] = (f32x4){0.f, 0.f, 0.f, 0.f};

  u16* sb = &Sbuf[wid][0];

  for (int kb = 0; kb < 4; ++kb) {
    bf16x8 kf[4][2], vf[4][2];
#pragma unroll
    for (int nt = 0; nt < 4; ++nt)
#pragma unroll
      for (int kc = 0; kc < 2; ++kc) {
        kf[nt][kc] = *reinterpret_cast<const bf16x8*>(&Kp[(qbase + kb * 64 + nt * 16 + lr) * 1536 + kc * 32 + lg * 8]);
        vf[nt][kc] = *reinterpret_cast<const bf16x8*>(&Vt[(nt * 16 + lr) * 32768L + kb * 64 + kc * 32 + lg * 8]);
      }

#pragma unroll
    for (int mt = 0; mt < 4; ++mt) {
      f32x4 sn[4];
#pragma unroll
      for (int nt = 0; nt < 4; ++nt) {
        f32x4 t = (f32x4){0.f, 0.f, 0.f, 0.f};
#pragma unroll
        for (int kc = 0; kc < 2; ++kc)
          t = __builtin_amdgcn_mfma_f32_16x16x32_bf16(qa[mt][kc], kf[nt][kc], t, 0, 0, 0);
        sn[nt] = t;
      }
#pragma unroll
      for (int r = 0; r < 4; ++r) {
        const int x = wid * 64 + mt * 16 + lg * 4 + r;
        float sv[4];
#pragma unroll
        for (int nt = 0; nt < 4; ++nt)
          sv[nt] = sn[nt][r] * 0.125f + bf2f(relh_s[x * 16 + kb * 4 + nt]) + rw[mt][r];
        float rmax = fmaxf(fmaxf(sv[0], sv[1]), fmaxf(sv[2], sv[3]));
        rmax = fmaxf(rmax, __shfl_xor(rmax, 1));
        rmax = fmaxf(rmax, __shfl_xor(rmax, 2));
        rmax = fmaxf(rmax, __shfl_xor(rmax, 4));
        rmax = fmaxf(rmax, __shfl_xor(rmax, 8));
        const float mnew = fmaxf(mrun[mt][r], rmax);
        const float sf = __expf(mrun[mt][r] - mnew);   // lane-uniform (post-broadcast max)
        mrun[mt][r] = mnew;
        float rsum = 0.f;
#pragma unroll
        for (int nt = 0; nt < 4; ++nt) { const float p = __expf(sv[nt] - mnew); sv[nt] = p; rsum += p; }
        // deferred sum-reduce: keep per-lane partial; butterfly once in epilogue
        lrun[mt][r] = lrun[mt][r] * sf + rsum;
#pragma unroll
        for (int nt = 0; nt < 4; ++nt) oacc[mt][nt][r] *= sf;
        const int rowl = lg * 4 + r;               // row within this 16-row mt-block
#pragma unroll
        for (int nt = 0; nt < 4; ++nt) sb[rowl * 72 + nt * 16 + lr] = f2bf(sv[nt]);
      }
      // ---- PV for this mt-block (same-wave LDS write->read; compiler inserts lgkmcnt) ----
#pragma unroll
      for (int kc = 0; kc < 2; ++kc) {
        bf16x8 pa = *reinterpret_cast<const bf16x8*>(&sb[lr * 72 + kc * 32 + lg * 8]);
#pragma unroll
        for (int nt = 0; nt < 4; ++nt)
          oacc[mt][nt] = __builtin_amdgcn_mfma_f32_16x16x32_bf16(pa, vf[nt][kc], oacc[mt][nt], 0, 0, 0);
      }
    }
  }

  // ---- epilogue: reduce lrun partials across the 16-lane row group, then O/l ----
#pragma unroll
  for (int mt = 0; mt < 4; ++mt)
#pragma unroll
    for (int r = 0; r < 4; ++r) {
      float lt = lrun[mt][r];
      lt += __shfl_xor(lt, 1);
      lt += __shfl_xor(lt, 2);
      lt += __shfl_xor(lt, 4);
      lt += __shfl_xor(lt, 8);
      const float inv = 1.f / lt;
      const long row = qbase + wid * 64 + mt * 16 + lg * 4 + r;
#pragma unroll
      for (int nt = 0; nt < 4; ++nt)
        oatt[row * 768 + h * 64 + nt * 16 + lr] = f2bf(oacc[mt][nt][r] * inv);
    }
}

extern "C" void kernel_launch(void* const* d_in, const int* in_sizes, int n_in,
                              void* d_out, int out_size, void* d_ws, size_t ws_size,
                              hipStream_t stream) {
  (void)in_sizes; (void)n_in; (void)out_size; (void)ws_size;
  const float* x     = (const float*)d_in[0];
  const float* w_qkv = (const float*)d_in[1];
  const float* w_out = (const float*)d_in[2];
  const float* b_out = (const float*)d_in[3];
  const float* rph   = (const float*)d_in[4];
  const float* rpw   = (const float*)d_in[5];
  float* out = (float*)d_out;

  char* ws = (char*)d_ws;
  u16* qk    = (u16*)ws;                              // 32768*1536 bf16 = 100.7 MB (q,k row-major)
  u16* vT    = (u16*)(ws + 100663296L);               // 768*32768  bf16 =  50.3 MB (v transposed)
  u16* xw    = (u16*)(ws + 150994944L);               // 32768*768  bf16 =  50.3 MB (reused as oatt)
  u16* wqkvb = (u16*)(ws + 201326592L);               // 2304*768 bf16
  u16* woutb = (u16*)(ws + 204865536L);               //  768*768 bf16; total 206,045,184 B
  u16* oatt  = xw;                                    // xw is dead after gemm1

  sab_cvt_kernel<<<dim3(1728), dim3(256), 0, stream>>>(w_qkv, wqkvb, 442368);
  sab_cvt_kernel<<<dim3(576), dim3(256), 0, stream>>>(w_out, woutb, 147456);
  sab_xw_kernel<<<dim3(32768), dim3(192), 0, stream>>>(x, xw);
  sab_gemm8_kernel<0><<<dim3(128, 9), dim3(512), 0, stream>>>(xw, wqkvb, qk, vT, nullptr, nullptr, 768);
  sab_attn_kernel<<<dim3(1536), dim3(256), 0, stream>>>(qk, vT, rph, rpw, oatt);
  sab_gemm8_kernel<1><<<dim3(128, 3), dim3(512), 0, stream>>>(oatt, woutb, nullptr, nullptr, out, b_out, 768);
}